// Round 13
// baseline (478.297 us; speedup 1.0000x reference)
//
#include <hip/hip_runtime.h>
#include <hip/hip_fp16.h>
#include <math.h>

// Problem constants
#define NN   20000     // nodes
#define NE   320000    // edges
#define NIN  128       // node input dim
#define HC   256       // heads(4) * hidden(64)
#define NB   1024      // fused GEMM output width: [q | kv-interleaved | qproj]

typedef unsigned short u16;
typedef __attribute__((ext_vector_type(8))) short bf16x8;
typedef __attribute__((ext_vector_type(8))) unsigned short u16x8;
typedef __attribute__((ext_vector_type(4))) float f32x4;

__device__ __forceinline__ float bf2f(u16 u) {
  union { unsigned int i; float f; } x;
  x.i = ((unsigned int)u) << 16;
  return x.f;
}
__device__ __forceinline__ u16 f2bf(float f) {
  union { float f; unsigned int i; } x;
  x.f = f;
  unsigned int r = x.i + 0x7fffu + ((x.i >> 16) & 1u);
  return (u16)(r >> 16);
}

// dtype-flexible loads (flags detected on device each launch)
__device__ __forceinline__ float ldf(const void* p, int i, bool fbf) {
  return fbf ? bf2f(((const u16*)p)[i]) : ((const float*)p)[i];
}
__device__ __forceinline__ int ldsrc(const void* p, int e, bool is64) {
  const int* p32 = (const int*)p;
  return is64 ? p32[2 * e] : p32[e];
}
__device__ __forceinline__ int lddst(const void* p, int e, bool is64) {
  const int* p32 = (const int*)p;
  return is64 ? p32[2 * (NE + e)] : p32[NE + e];
}
__device__ __forceinline__ void stout(void* p, int i, float v, bool fbf) {
  if (fbf) ((u16*)p)[i] = f2bf(v);
  else ((float*)p)[i] = v;
}

// ---------------- detection + div_term init ----------------
__global__ void devinit_kernel(const void* __restrict__ eidx,
                               const void* __restrict__ nemb,
                               int* __restrict__ flags, float* __restrict__ divt) {
  int lane = threadIdx.x;
  if (lane < 32) {
    const float c32 = (float)(-0.14391156831212787);
    float prod = (float)(2 * lane) * c32;
    divt[lane] = (float)exp((double)prod);
  }
  if (lane == 0) {
    const int* p32 = (const int*)eidx;
    int is64 = 1;
    for (int i = 1; i < 128; i += 2)
      if (p32[i] != 0) { is64 = 0; break; }
    const u16* q16 = (const u16*)nemb;
    int fbf = 1;
    for (int i = 0; i < 128; i += 2) {
      unsigned e = (q16[i] >> 7) & 0xFF;
      if (e < 90 || e > 140) { fbf = 0; break; }
    }
    flags[0] = is64;
    flags[1] = fbf;
  }
}

__global__ void sentinel_kernel(const int* __restrict__ flags, void* __restrict__ out) {
  int i = blockIdx.x * 256 + threadIdx.x;
  if (i < NE) stout(out, i, 3000.0f, flags[1] != 0);
}
__global__ void raw_sentinel_kernel(u16* __restrict__ out) {
  int i = blockIdx.x * 256 + threadIdx.x;
  if (i < NE) out[i] = f2bf(3000.0f);
}

// ---------------- CSR build ----------------
__global__ void zero_kernel(int* __restrict__ p, int n) {
  int i = blockIdx.x * 256 + threadIdx.x;
  if (i < n) p[i] = 0;
}

__global__ void hist_kernel(const int* __restrict__ flags, const void* __restrict__ eidx,
                            int* __restrict__ cnt) {
  bool is64 = flags[0] != 0;
  int e = blockIdx.x * 256 + threadIdx.x;
  if (e < NE) {
    int d = lddst(eidx, e, is64);
    if ((unsigned)d < NN) atomicAdd(&cnt[d], 1);
  }
}

// hierarchical scan
__global__ void scan1_kernel(const int* __restrict__ cnt, int* __restrict__ offs,
                             int* __restrict__ bsum, int n) {
  __shared__ int s[256];
  int b = blockIdx.x, t = threadIdx.x, i = b * 256 + t;
  int x = (i < n) ? cnt[i] : 0;
  s[t] = x;
  __syncthreads();
  for (int off = 1; off < 256; off <<= 1) {
    int y = (t >= off) ? s[t - off] : 0;
    __syncthreads();
    s[t] += y;
    __syncthreads();
  }
  if (i < n) offs[i] = s[t] - x;
  if (t == 255) bsum[b] = s[t];
}

__global__ void scan2_kernel(int* __restrict__ bsum, int* __restrict__ offs,
                             int nb, int n) {
  __shared__ int s[256];
  int t = threadIdx.x;
  int x = (t < nb) ? bsum[t] : 0;
  s[t] = x;
  __syncthreads();
  for (int off = 1; off < 256; off <<= 1) {
    int y = (t >= off) ? s[t - off] : 0;
    __syncthreads();
    s[t] += y;
    __syncthreads();
  }
  if (t < nb) bsum[t] = s[t] - x;
  if (t == 255) offs[n] = s[t];
}

__global__ void scan3_kernel(int* __restrict__ offs, const int* __restrict__ bsum, int n) {
  int i = blockIdx.x * 256 + threadIdx.x;
  if (i < n) offs[i] += bsum[blockIdx.x];
}

__global__ void copy_kernel(const int* __restrict__ a, int* __restrict__ b, int n) {
  int i = blockIdx.x * 256 + threadIdx.x;
  if (i < n) b[i] = a[i];
}

// fill: also materialize src (ssrc) and noisy time (stt) in sorted order
__global__ void fill_kernel(const int* __restrict__ flags, const void* __restrict__ eidx,
                            const void* __restrict__ rawt, const void* __restrict__ noise,
                            int* __restrict__ cursor, int* __restrict__ esorted,
                            int* __restrict__ ssrc, float* __restrict__ stt) {
  bool is64 = flags[0] != 0, fbf = flags[1] != 0;
  int e = blockIdx.x * 256 + threadIdx.x;
  if (e < NE) {
    int d = lddst(eidx, e, is64);
    if ((unsigned)d < NN) {
      int pos = atomicAdd(&cursor[d], 1);
      if ((unsigned)pos < NE) {
        esorted[pos] = e;
        int src = ldsrc(eidx, e, is64);
        if ((unsigned)src >= NN) src = 0;
        ssrc[pos] = src;
        stt[pos] = ldf(rawt, e, fbf) + ldf(noise, e, fbf);
      }
    }
  }
}

// ---------------- te_s[p][64] (f16, sorted order) — computed ONCE ----------------
__global__ __launch_bounds__(256) void te_kernel(
    const float* __restrict__ stt, const float* __restrict__ divt,
    u16* __restrict__ te_s) {
  int p = blockIdx.x * 4 + (threadIdx.x >> 6);
  if (p >= NE) return;
  int j = threadIdx.x & 63;
  float tt = stt[p];
  float arg = tt * divt[j >> 1];
  float te = (j & 1) ? cosf(arg) : sinf(arg);
  __half hv = __float2half(te);
  te_s[(size_t)p * 64 + j] = *(u16*)&hv;
}

// ---------------- weight transpose: W[K,256] -> dst[256][K] bf16 ----------------
__global__ void transw_kernel(const int* __restrict__ flags, const void* __restrict__ W,
                              u16* __restrict__ dst, int K) {
  bool fbf = flags[1] != 0;
  __shared__ u16 tile[64][65];
  int kb = blockIdx.x * 64, cb = blockIdx.y * 64;
  int tx = threadIdx.x & 63, ty = threadIdx.x >> 6;
  for (int i = ty; i < 64; i += 4)
    tile[tx][i] = f2bf(ldf(W, (kb + i) * HC + cb + tx, fbf));
  __syncthreads();
  for (int i = ty; i < 64; i += 4)
    dst[(size_t)(cb + i) * K + kb + tx] = tile[i][tx];
}

// ---------------- Wcomb rows: Wout[j][c] = sum_mm wt[j&63][h*64+mm] * Wqt[h*64+mm][c]
__global__ void wcomb_kernel(const int* __restrict__ flags, const void* __restrict__ wt,
                             const u16* __restrict__ Wqt, u16* __restrict__ Wout, int K) {
  bool fbf = flags[1] != 0;
  __shared__ float wrow[64];
  int j = blockIdx.x;
  int h = j >> 6;
  int c = threadIdx.x;
  if (threadIdx.x < 64)
    wrow[threadIdx.x] = ldf(wt, (j & 63) * HC + h * 64 + threadIdx.x, fbf);
  __syncthreads();
  float s = 0.f;
#pragma unroll 8
  for (int mm = 0; mm < 64; ++mm)
    s += wrow[mm] * bf2f(Wqt[(size_t)(h * 64 + mm) * K + c]);
  Wout[(size_t)j * K + c] = f2bf(s);
}

// ---------------- biasBig = [bq|bk|bv|bcomb] ----------------
__global__ void biasbig_kernel(const int* __restrict__ flags, const void* __restrict__ bq,
                               const void* __restrict__ bk, const void* __restrict__ bv,
                               const void* __restrict__ wt, float* __restrict__ biasBig) {
  bool fbf = flags[1] != 0;
  int b = blockIdx.x, t = threadIdx.x;
  if (b < 3) {
    const void* p = (b == 0) ? bq : (b == 1) ? bk : bv;
    biasBig[b * 256 + t] = ldf(p, t, fbf);
  } else {
    int j = t, h = j >> 6;
    float s = 0.f;
    for (int mm = 0; mm < 64; ++mm)
      s += ldf(bq, h * 64 + mm, fbf) * ldf(wt, (j & 63) * HC + h * 64 + mm, fbf);
    biasBig[768 + j] = s;
  }
}

// ---------------- qbt[n,h] = q[n,h,:] . bt[h,:] (q from qkvp, stride NB) ----------
__global__ __launch_bounds__(256) void qbt_kernel(
    const int* __restrict__ flags, const u16* __restrict__ qkvp,
    const void* __restrict__ bt, float* __restrict__ qbt) {
  bool fbf = flags[1] != 0;
  int t = threadIdx.x;
  int n = blockIdx.x;
  int h = t >> 6, j = t & 63;
  float pb = bf2f(qkvp[(size_t)n * NB + t]) * ldf(bt, t, fbf);
  for (int off = 32; off; off >>= 1) pb += __shfl_xor(pb, off);
  if (j == 0) qbt[n * 4 + h] = pb;
}

// ---------------- fused MFMA GEMM: C[M,1024](bf16) = A[M,K] @ WtBig^T + biasBig ----
// Epilogue remaps k/v columns into interleaved layout:
//   logical col 256+cc (k) -> 256 + (cc>>2)*8 + (cc&3)
//   logical col 512+cc (v) -> 256 + (cc>>2)*8 + 4 + (cc&3)
template <bool AWS>
__global__ __launch_bounds__(256) void gemm_mfma(
    const int* __restrict__ flags, const void* __restrict__ Ap,
    const u16* __restrict__ Wt, const float* __restrict__ bias,
    u16* __restrict__ C, int M, int K) {
  bool fbf = flags[1] != 0;
  __shared__ u16 As[64][56];
  __shared__ u16 Bs[64][56];
  int tid = threadIdx.x;
  int rb = blockIdx.x * 64, cb = blockIdx.y * 64;
  int wave = tid >> 6, lane = tid & 63;
  int l15 = lane & 15, quad = lane >> 4;

  f32x4 acc[4];
#pragma unroll
  for (int mt = 0; mt < 4; ++mt)
#pragma unroll
    for (int r = 0; r < 4; ++r) acc[mt][r] = 0.f;

  int srow = tid >> 2;
  int skq  = (tid & 3) * 8;

  for (int kk = 0; kk < K; kk += 32) {
    bf16x8 av;
#pragma unroll
    for (int i = 0; i < 8; ++i) av[i] = 0;
    int grow = rb + srow;
    if (grow < M) {
      if constexpr (AWS) {
        av = *(const bf16x8*)((const u16*)Ap + (size_t)grow * K + kk + skq);
      } else {
        if (fbf) {
          av = *(const bf16x8*)((const u16*)Ap + (size_t)grow * K + kk + skq);
        } else {
          const float* A = (const float*)Ap + (size_t)grow * K + kk + skq;
#pragma unroll
          for (int i = 0; i < 8; ++i) av[i] = (short)f2bf(A[i]);
        }
      }
    }
    *(bf16x8*)&As[srow][skq] = av;
    *(bf16x8*)&Bs[srow][skq] =
        *(const bf16x8*)(Wt + (size_t)(cb + srow) * K + kk + skq);
    __syncthreads();

    bf16x8 bfrag = *(const bf16x8*)&Bs[wave * 16 + l15][quad * 8];
#pragma unroll
    for (int mt = 0; mt < 4; ++mt) {
      bf16x8 afrag = *(const bf16x8*)&As[mt * 16 + l15][quad * 8];
      acc[mt] = __builtin_amdgcn_mfma_f32_16x16x32_bf16(afrag, bfrag, acc[mt], 0, 0, 0);
    }
    __syncthreads();
  }

  int gcol = cb + wave * 16 + l15;
  float bv = bias[gcol];
  // kv-interleave remap
  int scol;
  if (gcol < 256) scol = gcol;
  else if (gcol < 512) { int cc = gcol - 256; scol = 256 + ((cc >> 2) << 3) + (cc & 3); }
  else if (gcol < 768) { int cc = gcol - 512; scol = 256 + ((cc >> 2) << 3) + 4 + (cc & 3); }
  else scol = gcol;
#pragma unroll
  for (int mt = 0; mt < 4; ++mt) {
#pragma unroll
    for (int r = 0; r < 4; ++r) {
      int grow = rb + mt * 16 + quad * 4 + r;
      if (grow < M) C[(size_t)grow * NB + scol] = f2bf(acc[mt][r] + bv);
    }
  }
}

// ---------------- fused alpha + ONLINE softmax + aggregation + relu, 4-edge unroll --
// kv interleaved: one 16B load per edge-lane fetches k[4]+v[4].
__global__ __launch_bounds__(256) void aggfused_kernel(
    const int* __restrict__ flags, const int* __restrict__ ssrc,
    const int* __restrict__ offsets, const u16* __restrict__ te_s,
    const u16* __restrict__ qkvp, const float* __restrict__ qbt,
    u16* __restrict__ xout) {
  int w = threadIdx.x >> 6;
  int n = blockIdx.x * 4 + w;
  if (n >= NN) return;
  int lane = threadIdx.x & 63;
  int h = lane >> 4;
  int c = lane * 4;
  int s0 = offsets[n], s1 = offsets[n + 1];
  if (s0 < 0) s0 = 0;
  if (s1 > NE) s1 = NE;

  ushort4 q4 = *(const ushort4*)(qkvp + (size_t)n * NB + c);
  ushort4 p4 = *(const ushort4*)(qkvp + (size_t)n * NB + 768 + c);
  float qx = bf2f(q4.x), qy = bf2f(q4.y), qz = bf2f(q4.z), qw = bf2f(q4.w);
  float px = bf2f(p4.x), py = bf2f(p4.y), pz = bf2f(p4.z), pw = bf2f(p4.w);
  float qb = qbt[n * 4 + h];
  int jb = c & 63;
  int kvoff = 256 + lane * 8;   // interleaved kv base for this lane

  float m = -INFINITY, denom = 0.f;
  float acc0 = 0.f, acc1 = 0.f, acc2 = 0.f, acc3 = 0.f;

#define ALPHA_OF(kv, t4, out_a, okflag)                                        \
  {                                                                            \
    float s = qx * bf2f((kv)[0]) + __half2float(*(__half*)&(t4).x) * px;       \
    s += qy * bf2f((kv)[1]) + __half2float(*(__half*)&(t4).y) * py;            \
    s += qz * bf2f((kv)[2]) + __half2float(*(__half*)&(t4).z) * pz;            \
    s += qw * bf2f((kv)[3]) + __half2float(*(__half*)&(t4).w) * pw;            \
    s += __shfl_xor(s, 1);                                                     \
    s += __shfl_xor(s, 2);                                                     \
    s += __shfl_xor(s, 4);                                                     \
    s += __shfl_xor(s, 8);                                                     \
    out_a = (okflag) ? (s + qb) * 0.125f : 0.f;                                \
  }

#define STATE_UPDATE(a, kv, okflag)                                            \
  {                                                                            \
    if ((a) > m) {                                                             \
      float sc = expf(m - (a));                                                \
      denom *= sc;                                                             \
      acc0 *= sc; acc1 *= sc; acc2 *= sc; acc3 *= sc;                          \
      m = (a);                                                                 \
    }                                                                          \
    float ea = expf((a) - m);                                                  \
    denom += ea;                                                               \
    if (okflag) {                                                              \
      acc0 += ea * bf2f((kv)[4]);                                              \
      acc1 += ea * bf2f((kv)[5]);                                              \
      acc2 += ea * bf2f((kv)[6]);                                              \
      acc3 += ea * bf2f((kv)[7]);                                              \
    }                                                                          \
  }

  int p = s0;
  for (; p + 3 < s1; p += 4) {
    int srcA = ssrc[p], srcB = ssrc[p + 1], srcC = ssrc[p + 2], srcD = ssrc[p + 3];
    bool okA = (unsigned)srcA < NN, okB = (unsigned)srcB < NN;
    bool okC = (unsigned)srcC < NN, okD = (unsigned)srcD < NN;
    if (!okA) srcA = 0;
    if (!okB) srcB = 0;
    if (!okC) srcC = 0;
    if (!okD) srcD = 0;
    u16x8 kvA = *(const u16x8*)(qkvp + (size_t)srcA * NB + kvoff);
    u16x8 kvB = *(const u16x8*)(qkvp + (size_t)srcB * NB + kvoff);
    u16x8 kvC = *(const u16x8*)(qkvp + (size_t)srcC * NB + kvoff);
    u16x8 kvD = *(const u16x8*)(qkvp + (size_t)srcD * NB + kvoff);
    ushort4 tA = *(const ushort4*)(te_s + (size_t)p * 64 + jb);
    ushort4 tB = *(const ushort4*)(te_s + (size_t)(p + 1) * 64 + jb);
    ushort4 tC = *(const ushort4*)(te_s + (size_t)(p + 2) * 64 + jb);
    ushort4 tD = *(const ushort4*)(te_s + (size_t)(p + 3) * 64 + jb);

    float aA, aB, aC, aD;
    ALPHA_OF(kvA, tA, aA, okA)
    ALPHA_OF(kvB, tB, aB, okB)
    ALPHA_OF(kvC, tC, aC, okC)
    ALPHA_OF(kvD, tD, aD, okD)
    STATE_UPDATE(aA, kvA, okA)
    STATE_UPDATE(aB, kvB, okB)
    STATE_UPDATE(aC, kvC, okC)
    STATE_UPDATE(aD, kvD, okD)
  }
  for (; p < s1; ++p) {
    int src = ssrc[p];
    bool ok = (unsigned)src < NN;
    if (!ok) src = 0;
    u16x8 kv = *(const u16x8*)(qkvp + (size_t)src * NB + kvoff);
    ushort4 t4 = *(const ushort4*)(te_s + (size_t)p * 64 + jb);
    float a;
    ALPHA_OF(kv, t4, a, ok)
    STATE_UPDATE(a, kv, ok)
  }
#undef ALPHA_OF
#undef STATE_UPDATE

  float inv = 1.f / (denom + 1e-16f);
  ushort4 r;
  r.x = f2bf(fmaxf(acc0 * inv, 0.f));
  r.y = f2bf(fmaxf(acc1 * inv, 0.f));
  r.z = f2bf(fmaxf(acc2 * inv, 0.f));
  r.w = f2bf(fmaxf(acc3 * inv, 0.f));
  *(ushort4*)(xout + (size_t)n * HC + c) = r;
}

// ---------------- y[n] = x[n,:] . wc ----------------
__global__ __launch_bounds__(256) void xwc_kernel(
    const int* __restrict__ flags, const u16* __restrict__ x,
    const void* __restrict__ wc, float* __restrict__ y) {
  bool fbf = flags[1] != 0;
  int n = blockIdx.x * 4 + (threadIdx.x >> 6);
  if (n >= NN) return;
  int lane = threadIdx.x & 63;
  int c = lane * 4;
  ushort4 x4 = *(const ushort4*)(x + (size_t)n * HC + c);
  float s = bf2f(x4.x) * ldf(wc, c + 0, fbf);
  s += bf2f(x4.y) * ldf(wc, c + 1, fbf);
  s += bf2f(x4.z) * ldf(wc, c + 2, fbf);
  s += bf2f(x4.w) * ldf(wc, c + 3, fbf);
  for (int off = 32; off; off >>= 1) s += __shfl_xor(s, off);
  if (lane == 0) y[n] = s;
}

// ---------------- out[e] = y[src] + y[dst] + bc ----------------
__global__ __launch_bounds__(256) void final2_kernel(
    const int* __restrict__ flags, const void* __restrict__ eidx,
    const float* __restrict__ y, const void* __restrict__ bc,
    void* __restrict__ out) {
  bool is64 = flags[0] != 0, fbf = flags[1] != 0;
  int e = blockIdx.x * 256 + threadIdx.x;
  if (e >= NE) return;
  int src = ldsrc(eidx, e, is64);
  int dst = lddst(eidx, e, is64);
  if ((unsigned)src >= NN) src = 0;
  if ((unsigned)dst >= NN) dst = 0;
  stout(out, e, y[src] + y[dst] + ldf(bc, 0, fbf), fbf);
}

extern "C" void kernel_launch(void* const* d_in, const int* in_sizes, int n_in,
                              void* d_out, int out_size, void* d_ws, size_t ws_size,
                              hipStream_t stream) {
  const void* eidx  = d_in[0];
  const void* rawt  = d_in[1];
  const void* noise = d_in[2];
  const void* nemb  = d_in[3];
  const void *wq1 = d_in[4],  *bq1 = d_in[5];
  const void *wk1 = d_in[6],  *bk1 = d_in[7];
  const void *wv1 = d_in[8],  *bv1 = d_in[9];
  const void *wt1 = d_in[10], *bt1 = d_in[11];
  const void *wq2 = d_in[12], *bq2 = d_in[13];
  const void *wk2 = d_in[14], *bk2 = d_in[15];
  const void *wv2 = d_in[16], *bv2 = d_in[17];
  const void *wt2 = d_in[18], *bt2 = d_in[19];
  const void *wcp = d_in[20], *bcp = d_in[21];

  char* ws = (char*)d_ws;
  size_t off = 0;
  auto alloc = [&](size_t bytes) -> void* {
    void* p = ws + off;
    off += (bytes + 255) & ~(size_t)255;
    return p;
  };
  int*   flags  = (int*)alloc(256);
  float* divt   = (float*)alloc(256);
  u16*   WtBig  = (u16*)alloc((size_t)NB * HC * 2);
  float* biasBig= (float*)alloc((size_t)NB * 4);
  u16*   qkvp   = (u16*)alloc((size_t)NN * NB * 2);
  u16*   x1     = (u16*)alloc((size_t)NN * HC * 2);
  u16*   x2     = (u16*)alloc((size_t)NN * HC * 2);
  float* qbt    = (float*)alloc((size_t)NN * 4 * 4);
  float* ynode  = (float*)alloc((size_t)NN * 4);
  int* offsets  = (int*)alloc((size_t)(NN + 1) * 4);
  int* cursor   = (int*)alloc((size_t)NN * 4);
  int* bsum     = (int*)alloc(256 * 4);
  int* esorted  = (int*)alloc((size_t)NE * 4);
  int* ssrc     = (int*)alloc((size_t)NE * 4);
  float* stt    = (float*)alloc((size_t)NE * 4);
  u16* te_s     = (u16*)alloc((size_t)NE * 64 * 2);
  size_t need = off;

  int gN = (NN + 255) / 256, gE = (NE + 255) / 256;
  int nb = (NN + 255) / 256;

  if (ws_size < 1024) {
    raw_sentinel_kernel<<<gE, 256, 0, stream>>>((u16*)d_out);
    return;
  }
  devinit_kernel<<<1, 64, 0, stream>>>(eidx, nemb, flags, divt);
  if (need > ws_size) {
    sentinel_kernel<<<gE, 256, 0, stream>>>(flags, d_out);
    return;
  }

  // CSR by dst (+ sorted src / time)
  zero_kernel<<<gN, 256, 0, stream>>>(cursor, NN);
  hist_kernel<<<gE, 256, 0, stream>>>(flags, eidx, cursor);
  scan1_kernel<<<nb, 256, 0, stream>>>(cursor, offsets, bsum, NN);
  scan2_kernel<<<1, 256, 0, stream>>>(bsum, offsets, nb, NN);
  scan3_kernel<<<nb, 256, 0, stream>>>(offsets, bsum, NN);
  copy_kernel<<<gN, 256, 0, stream>>>(offsets, cursor, NN);
  fill_kernel<<<gE, 256, 0, stream>>>(flags, eidx, rawt, noise, cursor, esorted, ssrc, stt);

  int gEdge4 = (NE + 3) / 4;
  te_kernel<<<gEdge4, 256, 0, stream>>>(stt, divt, te_s);   // once for both layers

  dim3 ggemm((NN + 63) / 64, NB / 64);   // 313 x 16
  dim3 gt1(NIN / 64, 4), gt2(HC / 64, 4);
  int gNode = (NN + 3) / 4;

  // ---- Layer 1 (A = raw node_emb, K=128) ----
  transw_kernel<<<gt1, 256, 0, stream>>>(flags, wq1, WtBig + 0 * NIN, NIN);
  transw_kernel<<<gt1, 256, 0, stream>>>(flags, wk1, WtBig + (size_t)256 * NIN, NIN);
  transw_kernel<<<gt1, 256, 0, stream>>>(flags, wv1, WtBig + (size_t)512 * NIN, NIN);
  wcomb_kernel<<<256, NIN, 0, stream>>>(flags, wt1, WtBig, WtBig + (size_t)768 * NIN, NIN);
  biasbig_kernel<<<4, 256, 0, stream>>>(flags, bq1, bk1, bv1, wt1, biasBig);
  gemm_mfma<false><<<ggemm, 256, 0, stream>>>(flags, nemb, WtBig, biasBig, qkvp, NN, NIN);
  qbt_kernel<<<NN, 256, 0, stream>>>(flags, qkvp, bt1, qbt);
  aggfused_kernel<<<gNode, 256, 0, stream>>>(flags, ssrc, offsets, te_s, qkvp, qbt, x1);

  // ---- Layer 2 (A = bf16 x1, K=256) ----
  transw_kernel<<<gt2, 256, 0, stream>>>(flags, wq2, WtBig + 0 * HC, HC);
  transw_kernel<<<gt2, 256, 0, stream>>>(flags, wk2, WtBig + (size_t)256 * HC, HC);
  transw_kernel<<<gt2, 256, 0, stream>>>(flags, wv2, WtBig + (size_t)512 * HC, HC);
  wcomb_kernel<<<256, HC, 0, stream>>>(flags, wt2, WtBig, WtBig + (size_t)768 * HC, HC);
  biasbig_kernel<<<4, 256, 0, stream>>>(flags, bq2, bk2, bv2, wt2, biasBig);
  gemm_mfma<true><<<ggemm, 256, 0, stream>>>(flags, x1, WtBig, biasBig, qkvp, NN, HC);
  qbt_kernel<<<NN, 256, 0, stream>>>(flags, qkvp, bt2, qbt);
  aggfused_kernel<<<gNode, 256, 0, stream>>>(flags, ssrc, offsets, te_s, qkvp, qbt, x2);

  // Edge scorer: y[n] = x2[n].wc, then out[e] = y[src]+y[dst]+bc
  xwc_kernel<<<gNode, 256, 0, stream>>>(flags, x2, wcp, ynode);
  final2_kernel<<<gE, 256, 0, stream>>>(flags, eidx, ynode, bcp, d_out);
}

// Round 14
// 457.184 us; speedup vs baseline: 1.0462x; 1.0462x over previous
//
#include <hip/hip_runtime.h>
#include <hip/hip_fp16.h>
#include <math.h>

// Problem constants
#define NN   20000     // nodes
#define NE   320000    // edges
#define NIN  128       // node input dim
#define HC   256       // heads(4) * hidden(64)
#define NB   1024      // fused GEMM output width: [q | kv-interleaved | qproj]

typedef unsigned short u16;
typedef __attribute__((ext_vector_type(8))) short bf16x8;
typedef __attribute__((ext_vector_type(8))) unsigned short u16x8;
typedef __attribute__((ext_vector_type(4))) float f32x4;

__device__ __forceinline__ float bf2f(u16 u) {
  union { unsigned int i; float f; } x;
  x.i = ((unsigned int)u) << 16;
  return x.f;
}
__device__ __forceinline__ u16 f2bf(float f) {
  union { float f; unsigned int i; } x;
  x.f = f;
  unsigned int r = x.i + 0x7fffu + ((x.i >> 16) & 1u);
  return (u16)(r >> 16);
}

// dtype-flexible loads (flags detected on device each launch)
__device__ __forceinline__ float ldf(const void* p, int i, bool fbf) {
  return fbf ? bf2f(((const u16*)p)[i]) : ((const float*)p)[i];
}
__device__ __forceinline__ int ldsrc(const void* p, int e, bool is64) {
  const int* p32 = (const int*)p;
  return is64 ? p32[2 * e] : p32[e];
}
__device__ __forceinline__ int lddst(const void* p, int e, bool is64) {
  const int* p32 = (const int*)p;
  return is64 ? p32[2 * (NE + e)] : p32[NE + e];
}
__device__ __forceinline__ void stout(void* p, int i, float v, bool fbf) {
  if (fbf) ((u16*)p)[i] = f2bf(v);
  else ((float*)p)[i] = v;
}

// ---------------- detection + div_term init ----------------
__global__ void devinit_kernel(const void* __restrict__ eidx,
                               const void* __restrict__ nemb,
                               int* __restrict__ flags, float* __restrict__ divt) {
  int lane = threadIdx.x;
  if (lane < 32) {
    const float c32 = (float)(-0.14391156831212787);
    float prod = (float)(2 * lane) * c32;
    divt[lane] = (float)exp((double)prod);
  }
  if (lane == 0) {
    const int* p32 = (const int*)eidx;
    int is64 = 1;
    for (int i = 1; i < 128; i += 2)
      if (p32[i] != 0) { is64 = 0; break; }
    const u16* q16 = (const u16*)nemb;
    int fbf = 1;
    for (int i = 0; i < 128; i += 2) {
      unsigned e = (q16[i] >> 7) & 0xFF;
      if (e < 90 || e > 140) { fbf = 0; break; }
    }
    flags[0] = is64;
    flags[1] = fbf;
  }
}

__global__ void sentinel_kernel(const int* __restrict__ flags, void* __restrict__ out) {
  int i = blockIdx.x * 256 + threadIdx.x;
  if (i < NE) stout(out, i, 3000.0f, flags[1] != 0);
}
__global__ void raw_sentinel_kernel(u16* __restrict__ out) {
  int i = blockIdx.x * 256 + threadIdx.x;
  if (i < NE) out[i] = f2bf(3000.0f);
}

// ---------------- CSR build ----------------
__global__ void zero_kernel(int* __restrict__ p, int n) {
  int i = blockIdx.x * 256 + threadIdx.x;
  if (i < n) p[i] = 0;
}

__global__ void hist_kernel(const int* __restrict__ flags, const void* __restrict__ eidx,
                            int* __restrict__ cnt) {
  bool is64 = flags[0] != 0;
  int e = blockIdx.x * 256 + threadIdx.x;
  if (e < NE) {
    int d = lddst(eidx, e, is64);
    if ((unsigned)d < NN) atomicAdd(&cnt[d], 1);
  }
}

// hierarchical scan
__global__ void scan1_kernel(const int* __restrict__ cnt, int* __restrict__ offs,
                             int* __restrict__ bsum, int n) {
  __shared__ int s[256];
  int b = blockIdx.x, t = threadIdx.x, i = b * 256 + t;
  int x = (i < n) ? cnt[i] : 0;
  s[t] = x;
  __syncthreads();
  for (int off = 1; off < 256; off <<= 1) {
    int y = (t >= off) ? s[t - off] : 0;
    __syncthreads();
    s[t] += y;
    __syncthreads();
  }
  if (i < n) offs[i] = s[t] - x;
  if (t == 255) bsum[b] = s[t];
}

__global__ void scan2_kernel(int* __restrict__ bsum, int* __restrict__ offs,
                             int nb, int n) {
  __shared__ int s[256];
  int t = threadIdx.x;
  int x = (t < nb) ? bsum[t] : 0;
  s[t] = x;
  __syncthreads();
  for (int off = 1; off < 256; off <<= 1) {
    int y = (t >= off) ? s[t - off] : 0;
    __syncthreads();
    s[t] += y;
    __syncthreads();
  }
  if (t < nb) bsum[t] = s[t] - x;
  if (t == 255) offs[n] = s[t];
}

__global__ void scan3_kernel(int* __restrict__ offs, const int* __restrict__ bsum, int n) {
  int i = blockIdx.x * 256 + threadIdx.x;
  if (i < n) offs[i] += bsum[blockIdx.x];
}

__global__ void copy_kernel(const int* __restrict__ a, int* __restrict__ b, int n) {
  int i = blockIdx.x * 256 + threadIdx.x;
  if (i < n) b[i] = a[i];
}

// fill: also materialize src (ssrc) and noisy time (stt) in sorted order
__global__ void fill_kernel(const int* __restrict__ flags, const void* __restrict__ eidx,
                            const void* __restrict__ rawt, const void* __restrict__ noise,
                            int* __restrict__ cursor, int* __restrict__ esorted,
                            int* __restrict__ ssrc, float* __restrict__ stt) {
  bool is64 = flags[0] != 0, fbf = flags[1] != 0;
  int e = blockIdx.x * 256 + threadIdx.x;
  if (e < NE) {
    int d = lddst(eidx, e, is64);
    if ((unsigned)d < NN) {
      int pos = atomicAdd(&cursor[d], 1);
      if ((unsigned)pos < NE) {
        esorted[pos] = e;
        int src = ldsrc(eidx, e, is64);
        if ((unsigned)src >= NN) src = 0;
        ssrc[pos] = src;
        stt[pos] = ldf(rawt, e, fbf) + ldf(noise, e, fbf);
      }
    }
  }
}

// ---------------- te_s[p][64] (f16, sorted order) — sincos-paired, ONCE ----------
// thread = (edge p, freq f): one sincosf covers channels 2f (sin) and 2f+1 (cos).
__global__ __launch_bounds__(256) void te_kernel(
    const float* __restrict__ stt, const float* __restrict__ divt,
    u16* __restrict__ te_s) {
  int idx = blockIdx.x * 256 + threadIdx.x;
  int p = idx >> 5;          // 32 freqs per edge
  if (p >= NE) return;
  int f = idx & 31;
  float tt = stt[p];
  float arg = tt * divt[f];
  float sv, cv;
  sincosf(arg, &sv, &cv);
  __half hs = __float2half(sv), hc = __float2half(cv);
  unsigned int packed = (unsigned int)(*(u16*)&hs) | ((unsigned int)(*(u16*)&hc) << 16);
  ((unsigned int*)te_s)[(size_t)p * 32 + f] = packed;
}

// ---------------- weight transpose: W[K,256] -> dst[256][K] bf16 ----------------
__global__ void transw_kernel(const int* __restrict__ flags, const void* __restrict__ W,
                              u16* __restrict__ dst, int K) {
  bool fbf = flags[1] != 0;
  __shared__ u16 tile[64][65];
  int kb = blockIdx.x * 64, cb = blockIdx.y * 64;
  int tx = threadIdx.x & 63, ty = threadIdx.x >> 6;
  for (int i = ty; i < 64; i += 4)
    tile[tx][i] = f2bf(ldf(W, (kb + i) * HC + cb + tx, fbf));
  __syncthreads();
  for (int i = ty; i < 64; i += 4)
    dst[(size_t)(cb + i) * K + kb + tx] = tile[i][tx];
}

// ---------------- Wcomb rows: Wout[j][c] = sum_mm wt[j&63][h*64+mm] * Wqt[h*64+mm][c]
__global__ void wcomb_kernel(const int* __restrict__ flags, const void* __restrict__ wt,
                             const u16* __restrict__ Wqt, u16* __restrict__ Wout, int K) {
  bool fbf = flags[1] != 0;
  __shared__ float wrow[64];
  int j = blockIdx.x;
  int h = j >> 6;
  int c = threadIdx.x;
  if (threadIdx.x < 64)
    wrow[threadIdx.x] = ldf(wt, (j & 63) * HC + h * 64 + threadIdx.x, fbf);
  __syncthreads();
  float s = 0.f;
#pragma unroll 8
  for (int mm = 0; mm < 64; ++mm)
    s += wrow[mm] * bf2f(Wqt[(size_t)(h * 64 + mm) * K + c]);
  Wout[(size_t)j * K + c] = f2bf(s);
}

// ---------------- biasBig = [bq|bk|bv|bcomb] ----------------
__global__ void biasbig_kernel(const int* __restrict__ flags, const void* __restrict__ bq,
                               const void* __restrict__ bk, const void* __restrict__ bv,
                               const void* __restrict__ wt, float* __restrict__ biasBig) {
  bool fbf = flags[1] != 0;
  int b = blockIdx.x, t = threadIdx.x;
  if (b < 3) {
    const void* p = (b == 0) ? bq : (b == 1) ? bk : bv;
    biasBig[b * 256 + t] = ldf(p, t, fbf);
  } else {
    int j = t, h = j >> 6;
    float s = 0.f;
    for (int mm = 0; mm < 64; ++mm)
      s += ldf(bq, h * 64 + mm, fbf) * ldf(wt, (j & 63) * HC + h * 64 + mm, fbf);
    biasBig[768 + j] = s;
  }
}

// ---------------- qbt[n,h] = q[n,h,:] . bt[h,:] (q from qkvp, stride NB) ----------
__global__ __launch_bounds__(256) void qbt_kernel(
    const int* __restrict__ flags, const u16* __restrict__ qkvp,
    const void* __restrict__ bt, float* __restrict__ qbt) {
  bool fbf = flags[1] != 0;
  int t = threadIdx.x;
  int n = blockIdx.x;
  int h = t >> 6, j = t & 63;
  float pb = bf2f(qkvp[(size_t)n * NB + t]) * ldf(bt, t, fbf);
  for (int off = 32; off; off >>= 1) pb += __shfl_xor(pb, off);
  if (j == 0) qbt[n * 4 + h] = pb;
}

// ---------------- fused MFMA GEMM: C[M,1024](bf16) = A[M,K] @ WtBig^T + biasBig ----
// Epilogue remaps k/v columns into interleaved layout:
//   logical col 256+cc (k) -> 256 + (cc>>2)*8 + (cc&3)
//   logical col 512+cc (v) -> 256 + (cc>>2)*8 + 4 + (cc&3)
template <bool AWS>
__global__ __launch_bounds__(256) void gemm_mfma(
    const int* __restrict__ flags, const void* __restrict__ Ap,
    const u16* __restrict__ Wt, const float* __restrict__ bias,
    u16* __restrict__ C, int M, int K) {
  bool fbf = flags[1] != 0;
  __shared__ u16 As[64][56];
  __shared__ u16 Bs[64][56];
  int tid = threadIdx.x;
  int rb = blockIdx.x * 64, cb = blockIdx.y * 64;
  int wave = tid >> 6, lane = tid & 63;
  int l15 = lane & 15, quad = lane >> 4;

  f32x4 acc[4];
#pragma unroll
  for (int mt = 0; mt < 4; ++mt)
#pragma unroll
    for (int r = 0; r < 4; ++r) acc[mt][r] = 0.f;

  int srow = tid >> 2;
  int skq  = (tid & 3) * 8;

  for (int kk = 0; kk < K; kk += 32) {
    bf16x8 av;
#pragma unroll
    for (int i = 0; i < 8; ++i) av[i] = 0;
    int grow = rb + srow;
    if (grow < M) {
      if constexpr (AWS) {
        av = *(const bf16x8*)((const u16*)Ap + (size_t)grow * K + kk + skq);
      } else {
        if (fbf) {
          av = *(const bf16x8*)((const u16*)Ap + (size_t)grow * K + kk + skq);
        } else {
          const float* A = (const float*)Ap + (size_t)grow * K + kk + skq;
#pragma unroll
          for (int i = 0; i < 8; ++i) av[i] = (short)f2bf(A[i]);
        }
      }
    }
    *(bf16x8*)&As[srow][skq] = av;
    *(bf16x8*)&Bs[srow][skq] =
        *(const bf16x8*)(Wt + (size_t)(cb + srow) * K + kk + skq);
    __syncthreads();

    bf16x8 bfrag = *(const bf16x8*)&Bs[wave * 16 + l15][quad * 8];
#pragma unroll
    for (int mt = 0; mt < 4; ++mt) {
      bf16x8 afrag = *(const bf16x8*)&As[mt * 16 + l15][quad * 8];
      acc[mt] = __builtin_amdgcn_mfma_f32_16x16x32_bf16(afrag, bfrag, acc[mt], 0, 0, 0);
    }
    __syncthreads();
  }

  int gcol = cb + wave * 16 + l15;
  float bv = bias[gcol];
  // kv-interleave remap
  int scol;
  if (gcol < 256) scol = gcol;
  else if (gcol < 512) { int cc = gcol - 256; scol = 256 + ((cc >> 2) << 3) + (cc & 3); }
  else if (gcol < 768) { int cc = gcol - 512; scol = 256 + ((cc >> 2) << 3) + 4 + (cc & 3); }
  else scol = gcol;
#pragma unroll
  for (int mt = 0; mt < 4; ++mt) {
#pragma unroll
    for (int r = 0; r < 4; ++r) {
      int grow = rb + mt * 16 + quad * 4 + r;
      if (grow < M) C[(size_t)grow * NB + scol] = f2bf(acc[mt][r] + bv);
    }
  }
}

// ---------------- fused alpha + ONLINE softmax + aggregation + relu, 4-edge unroll --
// Single-exp state update: new-max path uses ea=1.0 exactly (expf(0)=1 — bit-identical),
// else path computes one __expf. kv interleaved: one 16B load per edge-lane.
__global__ __launch_bounds__(256) void aggfused_kernel(
    const int* __restrict__ flags, const int* __restrict__ ssrc,
    const int* __restrict__ offsets, const u16* __restrict__ te_s,
    const u16* __restrict__ qkvp, const float* __restrict__ qbt,
    u16* __restrict__ xout) {
  int w = threadIdx.x >> 6;
  int n = blockIdx.x * 4 + w;
  if (n >= NN) return;
  int lane = threadIdx.x & 63;
  int h = lane >> 4;
  int c = lane * 4;
  int s0 = offsets[n], s1 = offsets[n + 1];
  if (s0 < 0) s0 = 0;
  if (s1 > NE) s1 = NE;

  ushort4 q4 = *(const ushort4*)(qkvp + (size_t)n * NB + c);
  ushort4 p4 = *(const ushort4*)(qkvp + (size_t)n * NB + 768 + c);
  float qx = bf2f(q4.x), qy = bf2f(q4.y), qz = bf2f(q4.z), qw = bf2f(q4.w);
  float px = bf2f(p4.x), py = bf2f(p4.y), pz = bf2f(p4.z), pw = bf2f(p4.w);
  float qb = qbt[n * 4 + h];
  int jb = c & 63;
  int kvoff = 256 + lane * 8;   // interleaved kv base for this lane

  float m = -INFINITY, denom = 0.f;
  float acc0 = 0.f, acc1 = 0.f, acc2 = 0.f, acc3 = 0.f;

#define ALPHA_OF(kv, t4, out_a, okflag)                                        \
  {                                                                            \
    float s = qx * bf2f((kv)[0]) + __half2float(*(__half*)&(t4).x) * px;       \
    s += qy * bf2f((kv)[1]) + __half2float(*(__half*)&(t4).y) * py;            \
    s += qz * bf2f((kv)[2]) + __half2float(*(__half*)&(t4).z) * pz;            \
    s += qw * bf2f((kv)[3]) + __half2float(*(__half*)&(t4).w) * pw;            \
    s += __shfl_xor(s, 1);                                                     \
    s += __shfl_xor(s, 2);                                                     \
    s += __shfl_xor(s, 4);                                                     \
    s += __shfl_xor(s, 8);                                                     \
    out_a = (okflag) ? (s + qb) * 0.125f : 0.f;                                \
  }

#define STATE_UPDATE(a, kv, okflag)                                            \
  {                                                                            \
    float ea;                                                                  \
    if ((a) > m) {                                                             \
      float sc = __expf(m - (a));     /* exp(-inf)=0 on first edge */          \
      denom *= sc;                                                             \
      acc0 *= sc; acc1 *= sc; acc2 *= sc; acc3 *= sc;                          \
      m = (a);                                                                 \
      ea = 1.0f;                      /* expf(0)==1 exactly */                 \
    } else {                                                                   \
      ea = __expf((a) - m);                                                    \
    }                                                                          \
    denom += ea;                                                               \
    if (okflag) {                                                              \
      acc0 += ea * bf2f((kv)[4]);                                              \
      acc1 += ea * bf2f((kv)[5]);                                              \
      acc2 += ea * bf2f((kv)[6]);                                              \
      acc3 += ea * bf2f((kv)[7]);                                              \
    }                                                                          \
  }

  int p = s0;
  for (; p + 3 < s1; p += 4) {
    int srcA = ssrc[p], srcB = ssrc[p + 1], srcC = ssrc[p + 2], srcD = ssrc[p + 3];
    bool okA = (unsigned)srcA < NN, okB = (unsigned)srcB < NN;
    bool okC = (unsigned)srcC < NN, okD = (unsigned)srcD < NN;
    if (!okA) srcA = 0;
    if (!okB) srcB = 0;
    if (!okC) srcC = 0;
    if (!okD) srcD = 0;
    u16x8 kvA = *(const u16x8*)(qkvp + (size_t)srcA * NB + kvoff);
    u16x8 kvB = *(const u16x8*)(qkvp + (size_t)srcB * NB + kvoff);
    u16x8 kvC = *(const u16x8*)(qkvp + (size_t)srcC * NB + kvoff);
    u16x8 kvD = *(const u16x8*)(qkvp + (size_t)srcD * NB + kvoff);
    ushort4 tA = *(const ushort4*)(te_s + (size_t)p * 64 + jb);
    ushort4 tB = *(const ushort4*)(te_s + (size_t)(p + 1) * 64 + jb);
    ushort4 tC = *(const ushort4*)(te_s + (size_t)(p + 2) * 64 + jb);
    ushort4 tD = *(const ushort4*)(te_s + (size_t)(p + 3) * 64 + jb);

    float aA, aB, aC, aD;
    ALPHA_OF(kvA, tA, aA, okA)
    ALPHA_OF(kvB, tB, aB, okB)
    ALPHA_OF(kvC, tC, aC, okC)
    ALPHA_OF(kvD, tD, aD, okD)
    STATE_UPDATE(aA, kvA, okA)
    STATE_UPDATE(aB, kvB, okB)
    STATE_UPDATE(aC, kvC, okC)
    STATE_UPDATE(aD, kvD, okD)
  }
  for (; p < s1; ++p) {
    int src = ssrc[p];
    bool ok = (unsigned)src < NN;
    if (!ok) src = 0;
    u16x8 kv = *(const u16x8*)(qkvp + (size_t)src * NB + kvoff);
    ushort4 t4 = *(const ushort4*)(te_s + (size_t)p * 64 + jb);
    float a;
    ALPHA_OF(kv, t4, a, ok)
    STATE_UPDATE(a, kv, ok)
  }
#undef ALPHA_OF
#undef STATE_UPDATE

  float inv = 1.f / (denom + 1e-16f);
  ushort4 r;
  r.x = f2bf(fmaxf(acc0 * inv, 0.f));
  r.y = f2bf(fmaxf(acc1 * inv, 0.f));
  r.z = f2bf(fmaxf(acc2 * inv, 0.f));
  r.w = f2bf(fmaxf(acc3 * inv, 0.f));
  *(ushort4*)(xout + (size_t)n * HC + c) = r;
}

// ---------------- y[n] = x[n,:] . wc ----------------
__global__ __launch_bounds__(256) void xwc_kernel(
    const int* __restrict__ flags, const u16* __restrict__ x,
    const void* __restrict__ wc, float* __restrict__ y) {
  bool fbf = flags[1] != 0;
  int n = blockIdx.x * 4 + (threadIdx.x >> 6);
  if (n >= NN) return;
  int lane = threadIdx.x & 63;
  int c = lane * 4;
  ushort4 x4 = *(const ushort4*)(x + (size_t)n * HC + c);
  float s = bf2f(x4.x) * ldf(wc, c + 0, fbf);
  s += bf2f(x4.y) * ldf(wc, c + 1, fbf);
  s += bf2f(x4.z) * ldf(wc, c + 2, fbf);
  s += bf2f(x4.w) * ldf(wc, c + 3, fbf);
  for (int off = 32; off; off >>= 1) s += __shfl_xor(s, off);
  if (lane == 0) y[n] = s;
}

// ---------------- out[e] = y[src] + y[dst] + bc ----------------
__global__ __launch_bounds__(256) void final2_kernel(
    const int* __restrict__ flags, const void* __restrict__ eidx,
    const float* __restrict__ y, const void* __restrict__ bc,
    void* __restrict__ out) {
  bool is64 = flags[0] != 0, fbf = flags[1] != 0;
  int e = blockIdx.x * 256 + threadIdx.x;
  if (e >= NE) return;
  int src = ldsrc(eidx, e, is64);
  int dst = lddst(eidx, e, is64);
  if ((unsigned)src >= NN) src = 0;
  if ((unsigned)dst >= NN) dst = 0;
  stout(out, e, y[src] + y[dst] + ldf(bc, 0, fbf), fbf);
}

extern "C" void kernel_launch(void* const* d_in, const int* in_sizes, int n_in,
                              void* d_out, int out_size, void* d_ws, size_t ws_size,
                              hipStream_t stream) {
  const void* eidx  = d_in[0];
  const void* rawt  = d_in[1];
  const void* noise = d_in[2];
  const void* nemb  = d_in[3];
  const void *wq1 = d_in[4],  *bq1 = d_in[5];
  const void *wk1 = d_in[6],  *bk1 = d_in[7];
  const void *wv1 = d_in[8],  *bv1 = d_in[9];
  const void *wt1 = d_in[10], *bt1 = d_in[11];
  const void *wq2 = d_in[12], *bq2 = d_in[13];
  const void *wk2 = d_in[14], *bk2 = d_in[15];
  const void *wv2 = d_in[16], *bv2 = d_in[17];
  const void *wt2 = d_in[18], *bt2 = d_in[19];
  const void *wcp = d_in[20], *bcp = d_in[21];

  char* ws = (char*)d_ws;
  size_t off = 0;
  auto alloc = [&](size_t bytes) -> void* {
    void* p = ws + off;
    off += (bytes + 255) & ~(size_t)255;
    return p;
  };
  int*   flags  = (int*)alloc(256);
  float* divt   = (float*)alloc(256);
  u16*   WtBig  = (u16*)alloc((size_t)NB * HC * 2);
  float* biasBig= (float*)alloc((size_t)NB * 4);
  u16*   qkvp   = (u16*)alloc((size_t)NN * NB * 2);
  u16*   x1     = (u16*)alloc((size_t)NN * HC * 2);
  u16*   x2     = (u16*)alloc((size_t)NN * HC * 2);
  float* qbt    = (float*)alloc((size_t)NN * 4 * 4);
  float* ynode  = (float*)alloc((size_t)NN * 4);
  int* offsets  = (int*)alloc((size_t)(NN + 1) * 4);
  int* cursor   = (int*)alloc((size_t)NN * 4);
  int* bsum     = (int*)alloc(256 * 4);
  int* esorted  = (int*)alloc((size_t)NE * 4);
  int* ssrc     = (int*)alloc((size_t)NE * 4);
  float* stt    = (float*)alloc((size_t)NE * 4);
  u16* te_s     = (u16*)alloc((size_t)NE * 64 * 2);
  size_t need = off;

  int gN = (NN + 255) / 256, gE = (NE + 255) / 256;
  int nb = (NN + 255) / 256;

  if (ws_size < 1024) {
    raw_sentinel_kernel<<<gE, 256, 0, stream>>>((u16*)d_out);
    return;
  }
  devinit_kernel<<<1, 64, 0, stream>>>(eidx, nemb, flags, divt);
  if (need > ws_size) {
    sentinel_kernel<<<gE, 256, 0, stream>>>(flags, d_out);
    return;
  }

  // CSR by dst (+ sorted src / time)
  zero_kernel<<<gN, 256, 0, stream>>>(cursor, NN);
  hist_kernel<<<gE, 256, 0, stream>>>(flags, eidx, cursor);
  scan1_kernel<<<nb, 256, 0, stream>>>(cursor, offsets, bsum, NN);
  scan2_kernel<<<1, 256, 0, stream>>>(bsum, offsets, nb, NN);
  scan3_kernel<<<nb, 256, 0, stream>>>(offsets, bsum, NN);
  copy_kernel<<<gN, 256, 0, stream>>>(offsets, cursor, NN);
  fill_kernel<<<gE, 256, 0, stream>>>(flags, eidx, rawt, noise, cursor, esorted, ssrc, stt);

  int gTe = (NE * 32 + 255) / 256;
  te_kernel<<<gTe, 256, 0, stream>>>(stt, divt, te_s);   // once for both layers

  dim3 ggemm((NN + 63) / 64, NB / 64);   // 313 x 16
  dim3 gt1(NIN / 64, 4), gt2(HC / 64, 4);
  int gNode = (NN + 3) / 4;

  // ---- Layer 1 (A = raw node_emb, K=128) ----
  transw_kernel<<<gt1, 256, 0, stream>>>(flags, wq1, WtBig + 0 * NIN, NIN);
  transw_kernel<<<gt1, 256, 0, stream>>>(flags, wk1, WtBig + (size_t)256 * NIN, NIN);
  transw_kernel<<<gt1, 256, 0, stream>>>(flags, wv1, WtBig + (size_t)512 * NIN, NIN);
  wcomb_kernel<<<256, NIN, 0, stream>>>(flags, wt1, WtBig, WtBig + (size_t)768 * NIN, NIN);
  biasbig_kernel<<<4, 256, 0, stream>>>(flags, bq1, bk1, bv1, wt1, biasBig);
  gemm_mfma<false><<<ggemm, 256, 0, stream>>>(flags, nemb, WtBig, biasBig, qkvp, NN, NIN);
  qbt_kernel<<<NN, 256, 0, stream>>>(flags, qkvp, bt1, qbt);
  aggfused_kernel<<<gNode, 256, 0, stream>>>(flags, ssrc, offsets, te_s, qkvp, qbt, x1);

  // ---- Layer 2 (A = bf16 x1, K=256) ----
  transw_kernel<<<gt2, 256, 0, stream>>>(flags, wq2, WtBig + 0 * HC, HC);
  transw_kernel<<<gt2, 256, 0, stream>>>(flags, wk2, WtBig + (size_t)256 * HC, HC);
  transw_kernel<<<gt2, 256, 0, stream>>>(flags, wv2, WtBig + (size_t)512 * HC, HC);
  wcomb_kernel<<<256, HC, 0, stream>>>(flags, wt2, WtBig, WtBig + (size_t)768 * HC, HC);
  biasbig_kernel<<<4, 256, 0, stream>>>(flags, bq2, bk2, bv2, wt2, biasBig);
  gemm_mfma<true><<<ggemm, 256, 0, stream>>>(flags, x1, WtBig, biasBig, qkvp, NN, HC);
  qbt_kernel<<<NN, 256, 0, stream>>>(flags, qkvp, bt2, qbt);
  aggfused_kernel<<<gNode, 256, 0, stream>>>(flags, ssrc, offsets, te_s, qkvp, qbt, x2);

  // Edge scorer: y[n] = x2[n].wc, then out[e] = y[src]+y[dst]+bc
  xwc_kernel<<<gNode, 256, 0, stream>>>(flags, x2, wcp, ynode);
  final2_kernel<<<gE, 256, 0, stream>>>(flags, eidx, ynode, bcp, d_out);
}

// Round 15
// 398.827 us; speedup vs baseline: 1.1993x; 1.1463x over previous
//
#include <hip/hip_runtime.h>
#include <hip/hip_fp16.h>
#include <math.h>

// Problem constants
#define NN   20000     // nodes
#define NE   320000    // edges
#define NIN  128       // node input dim
#define HC   256       // heads(4) * hidden(64)
#define NB   1024      // fused GEMM output width: [q | kv-interleaved | qproj]

typedef unsigned short u16;
typedef __attribute__((ext_vector_type(8))) short bf16x8;
typedef __attribute__((ext_vector_type(8))) unsigned short u16x8;
typedef __attribute__((ext_vector_type(4))) float f32x4;

__device__ __forceinline__ float bf2f(u16 u) {
  union { unsigned int i; float f; } x;
  x.i = ((unsigned int)u) << 16;
  return x.f;
}
__device__ __forceinline__ u16 f2bf(float f) {
  union { float f; unsigned int i; } x;
  x.f = f;
  unsigned int r = x.i + 0x7fffu + ((x.i >> 16) & 1u);
  return (u16)(r >> 16);
}

// dtype-flexible loads (flags detected on device each launch)
__device__ __forceinline__ float ldf(const void* p, int i, bool fbf) {
  return fbf ? bf2f(((const u16*)p)[i]) : ((const float*)p)[i];
}
__device__ __forceinline__ int ldsrc(const void* p, int e, bool is64) {
  const int* p32 = (const int*)p;
  return is64 ? p32[2 * e] : p32[e];
}
__device__ __forceinline__ int lddst(const void* p, int e, bool is64) {
  const int* p32 = (const int*)p;
  return is64 ? p32[2 * (NE + e)] : p32[NE + e];
}
__device__ __forceinline__ void stout(void* p, int i, float v, bool fbf) {
  if (fbf) ((u16*)p)[i] = f2bf(v);
  else ((float*)p)[i] = v;
}

// async global->LDS, 16B per lane (wave-uniform LDS base + lane*16 layout)
__device__ __forceinline__ void gload_lds16(const u16* g, u16* l) {
  __builtin_amdgcn_global_load_lds(
      (const __attribute__((address_space(1))) void*)g,
      (__attribute__((address_space(3))) void*)l, 16, 0, 0);
}

// ---------------- detection + div_term init ----------------
__global__ void devinit_kernel(const void* __restrict__ eidx,
                               const void* __restrict__ nemb,
                               int* __restrict__ flags, float* __restrict__ divt) {
  int lane = threadIdx.x;
  if (lane < 32) {
    const float c32 = (float)(-0.14391156831212787);
    float prod = (float)(2 * lane) * c32;
    divt[lane] = (float)exp((double)prod);
  }
  if (lane == 0) {
    const int* p32 = (const int*)eidx;
    int is64 = 1;
    for (int i = 1; i < 128; i += 2)
      if (p32[i] != 0) { is64 = 0; break; }
    const u16* q16 = (const u16*)nemb;
    int fbf = 1;
    for (int i = 0; i < 128; i += 2) {
      unsigned e = (q16[i] >> 7) & 0xFF;
      if (e < 90 || e > 140) { fbf = 0; break; }
    }
    flags[0] = is64;
    flags[1] = fbf;
  }
}

__global__ void sentinel_kernel(const int* __restrict__ flags, void* __restrict__ out) {
  int i = blockIdx.x * 256 + threadIdx.x;
  if (i < NE) stout(out, i, 3000.0f, flags[1] != 0);
}
__global__ void raw_sentinel_kernel(u16* __restrict__ out) {
  int i = blockIdx.x * 256 + threadIdx.x;
  if (i < NE) out[i] = f2bf(3000.0f);
}

// ---------------- CSR build ----------------
__global__ void zero_kernel(int* __restrict__ p, int n) {
  int i = blockIdx.x * 256 + threadIdx.x;
  if (i < n) p[i] = 0;
}

__global__ void hist_kernel(const int* __restrict__ flags, const void* __restrict__ eidx,
                            int* __restrict__ cnt) {
  bool is64 = flags[0] != 0;
  int e = blockIdx.x * 256 + threadIdx.x;
  if (e < NE) {
    int d = lddst(eidx, e, is64);
    if ((unsigned)d < NN) atomicAdd(&cnt[d], 1);
  }
}

// hierarchical scan
__global__ void scan1_kernel(const int* __restrict__ cnt, int* __restrict__ offs,
                             int* __restrict__ bsum, int n) {
  __shared__ int s[256];
  int b = blockIdx.x, t = threadIdx.x, i = b * 256 + t;
  int x = (i < n) ? cnt[i] : 0;
  s[t] = x;
  __syncthreads();
  for (int off = 1; off < 256; off <<= 1) {
    int y = (t >= off) ? s[t - off] : 0;
    __syncthreads();
    s[t] += y;
    __syncthreads();
  }
  if (i < n) offs[i] = s[t] - x;
  if (t == 255) bsum[b] = s[t];
}

__global__ void scan2_kernel(int* __restrict__ bsum, int* __restrict__ offs,
                             int nb, int n) {
  __shared__ int s[256];
  int t = threadIdx.x;
  int x = (t < nb) ? bsum[t] : 0;
  s[t] = x;
  __syncthreads();
  for (int off = 1; off < 256; off <<= 1) {
    int y = (t >= off) ? s[t - off] : 0;
    __syncthreads();
    s[t] += y;
    __syncthreads();
  }
  if (t < nb) bsum[t] = s[t] - x;
  if (t == 255) offs[n] = s[t];
}

// scan3 + cursor init merged
__global__ void scan3_kernel(int* __restrict__ offs, const int* __restrict__ bsum,
                             int* __restrict__ cursor, int n) {
  int i = blockIdx.x * 256 + threadIdx.x;
  if (i < n) {
    int v = offs[i] + bsum[blockIdx.x];
    offs[i] = v;
    cursor[i] = v;
  }
}

// fill: materialize src (ssrc) and noisy time (stt) in sorted order
__global__ void fill_kernel(const int* __restrict__ flags, const void* __restrict__ eidx,
                            const void* __restrict__ rawt, const void* __restrict__ noise,
                            int* __restrict__ cursor, int* __restrict__ ssrc,
                            float* __restrict__ stt) {
  bool is64 = flags[0] != 0, fbf = flags[1] != 0;
  int e = blockIdx.x * 256 + threadIdx.x;
  if (e < NE) {
    int d = lddst(eidx, e, is64);
    if ((unsigned)d < NN) {
      int pos = atomicAdd(&cursor[d], 1);
      if ((unsigned)pos < NE) {
        int src = ldsrc(eidx, e, is64);
        if ((unsigned)src >= NN) src = 0;
        ssrc[pos] = src;
        stt[pos] = ldf(rawt, e, fbf) + ldf(noise, e, fbf);
      }
    }
  }
}

// ---------------- te_s[p][64] (f16, sorted order) — sincos-paired, ONCE ----------
__global__ __launch_bounds__(256) void te_kernel(
    const float* __restrict__ stt, const float* __restrict__ divt,
    u16* __restrict__ te_s) {
  int idx = blockIdx.x * 256 + threadIdx.x;
  int p = idx >> 5;          // 32 freqs per edge
  if (p >= NE) return;
  int f = idx & 31;
  float tt = stt[p];
  float arg = tt * divt[f];
  float sv, cv;
  sincosf(arg, &sv, &cv);
  __half hs = __float2half(sv), hc = __float2half(cv);
  unsigned int packed = (unsigned int)(*(u16*)&hs) | ((unsigned int)(*(u16*)&hc) << 16);
  ((unsigned int*)te_s)[(size_t)p * 32 + f] = packed;
}

// ---------------- merged weight transpose: 3 matrices -> WtBig rows 0/256/512 -----
__global__ void transw3_kernel(const int* __restrict__ flags, const void* __restrict__ W0,
                               const void* __restrict__ W1, const void* __restrict__ W2,
                               u16* __restrict__ WtBig, int K) {
  bool fbf = flags[1] != 0;
  __shared__ u16 tile[64][65];
  int z = blockIdx.z;
  const void* W = (z == 0) ? W0 : (z == 1) ? W1 : W2;
  u16* dst = WtBig + (size_t)z * 256 * K;
  int kb = blockIdx.x * 64, cb = blockIdx.y * 64;
  int tx = threadIdx.x & 63, ty = threadIdx.x >> 6;
  for (int i = ty; i < 64; i += 4)
    tile[tx][i] = f2bf(ldf(W, (kb + i) * HC + cb + tx, fbf));
  __syncthreads();
  for (int i = ty; i < 64; i += 4)
    dst[(size_t)(cb + i) * K + kb + tx] = tile[i][tx];
}

// ---------------- wcomb + biasBig merged ----------------
// blocks 0..255: Wout[j][c] = sum_mm wt[j&63][h*64+mm] * Wqt[h*64+mm][c]
// blocks 256..258: biasBig copy bq/bk/bv; block 259: bcomb
__global__ void wcombbias_kernel(const int* __restrict__ flags, const void* __restrict__ wt,
                                 const u16* __restrict__ Wqt, u16* __restrict__ Wout,
                                 const void* __restrict__ bq, const void* __restrict__ bk,
                                 const void* __restrict__ bv, float* __restrict__ biasBig,
                                 int K) {
  bool fbf = flags[1] != 0;
  int b = blockIdx.x, t = threadIdx.x;
  if (b < 256) {
    __shared__ float wrow[64];
    int j = b, h = j >> 6;
    if (t < 64) wrow[t] = ldf(wt, (j & 63) * HC + h * 64 + t, fbf);
    __syncthreads();
    if (t < K) {
      float s = 0.f;
#pragma unroll 8
      for (int mm = 0; mm < 64; ++mm)
        s += wrow[mm] * bf2f(Wqt[(size_t)(h * 64 + mm) * K + t]);
      Wout[(size_t)j * K + t] = f2bf(s);
    }
  } else if (b < 259) {
    int bb = b - 256;
    const void* p = (bb == 0) ? bq : (bb == 1) ? bk : bv;
    biasBig[bb * 256 + t] = ldf(p, t, fbf);
  } else {
    int j = t, h = j >> 6;
    float s = 0.f;
    for (int mm = 0; mm < 64; ++mm)
      s += ldf(bq, h * 64 + mm, fbf) * ldf(wt, (j & 63) * HC + h * 64 + mm, fbf);
    biasBig[768 + j] = s;
  }
}

// ---------------- fused MFMA GEMM: C[M,1024](bf16) = A[M,K] @ WtBig^T + biasBig ----
// Direct global->LDS staging (16B/lane), unpadded [64][32] tiles with source-chunk
// XOR swizzle (chunk ^= row&3) to break bank alignment; readers apply same swizzle.
// Epilogue remaps k/v columns into interleaved layout.
template <bool AWS>
__global__ __launch_bounds__(256) void gemm_mfma(
    const int* __restrict__ flags, const void* __restrict__ Ap,
    const u16* __restrict__ Wt, const float* __restrict__ bias,
    u16* __restrict__ C, int M, int K) {
  bool fbf = flags[1] != 0;
  __shared__ u16 As[64 * 32];
  __shared__ u16 Bs[64 * 32];
  int tid = threadIdx.x;
  int rb = blockIdx.x * 64, cb = blockIdx.y * 64;
  int wave = tid >> 6, lane = tid & 63;
  int l15 = lane & 15, quad = lane >> 4;

  f32x4 acc[4];
#pragma unroll
  for (int mt = 0; mt < 4; ++mt)
#pragma unroll
    for (int r = 0; r < 4; ++r) acc[mt][r] = 0.f;

  int srow = tid >> 2;                 // 0..63
  int schunk = tid & 3;                // LDS 16B chunk slot within row
  int gchunk = schunk ^ (srow & 3);    // source chunk (swizzle)
  int arow = rb + srow; if (arow >= M) arow = M - 1;   // clamp (rows>=M not stored)
  u16* asl = &As[srow * 32 + schunk * 8];
  u16* bsl = &Bs[srow * 32 + schunk * 8];
  const u16* bsrc = Wt + (size_t)(cb + srow) * K + gchunk * 8;
  const bool adirect = AWS || fbf;
  const u16* asrc = adirect ? ((const u16*)Ap + (size_t)arow * K + gchunk * 8) : (const u16*)0;

  for (int kk = 0; kk < K; kk += 32) {
    if (adirect) {
      gload_lds16(asrc + kk, asl);
    } else {
      const float* A = (const float*)Ap + (size_t)arow * K + kk + gchunk * 8;
      bf16x8 tmp;
#pragma unroll
      for (int i = 0; i < 8; ++i) tmp[i] = (short)f2bf(A[i]);
      *(bf16x8*)asl = tmp;
    }
    gload_lds16(bsrc + kk, bsl);
    __syncthreads();

    int bcol = wave * 16 + l15;
    bf16x8 bfrag = *(const bf16x8*)&Bs[bcol * 32 + ((quad ^ (bcol & 3)) * 8)];
#pragma unroll
    for (int mt = 0; mt < 4; ++mt) {
      int ar = mt * 16 + l15;
      bf16x8 afrag = *(const bf16x8*)&As[ar * 32 + ((quad ^ (ar & 3)) * 8)];
      acc[mt] = __builtin_amdgcn_mfma_f32_16x16x32_bf16(afrag, bfrag, acc[mt], 0, 0, 0);
    }
    __syncthreads();
  }

  int gcol = cb + wave * 16 + l15;
  float bv = bias[gcol];
  // kv-interleave remap
  int scol;
  if (gcol < 256) scol = gcol;
  else if (gcol < 512) { int cc = gcol - 256; scol = 256 + ((cc >> 2) << 3) + (cc & 3); }
  else if (gcol < 768) { int cc = gcol - 512; scol = 256 + ((cc >> 2) << 3) + 4 + (cc & 3); }
  else scol = gcol;
#pragma unroll
  for (int mt = 0; mt < 4; ++mt) {
#pragma unroll
    for (int r = 0; r < 4; ++r) {
      int grow = rb + mt * 16 + quad * 4 + r;
      if (grow < M) C[(size_t)grow * NB + scol] = f2bf(acc[mt][r] + bv);
    }
  }
}

// ---------------- fused alpha + ONLINE softmax + aggregation + relu, 4-edge unroll --
// qbt folded in: each lane computes q·bt partial for its 4 channels, 16-lane reduce.
__global__ __launch_bounds__(256) void aggfused_kernel(
    const int* __restrict__ flags, const int* __restrict__ ssrc,
    const int* __restrict__ offsets, const u16* __restrict__ te_s,
    const u16* __restrict__ qkvp, const void* __restrict__ bt,
    u16* __restrict__ xout) {
  bool fbf = flags[1] != 0;
  int w = threadIdx.x >> 6;
  int n = blockIdx.x * 4 + w;
  if (n >= NN) return;
  int lane = threadIdx.x & 63;
  int c = lane * 4;
  int s0 = offsets[n], s1 = offsets[n + 1];
  if (s0 < 0) s0 = 0;
  if (s1 > NE) s1 = NE;

  ushort4 q4 = *(const ushort4*)(qkvp + (size_t)n * NB + c);
  ushort4 p4 = *(const ushort4*)(qkvp + (size_t)n * NB + 768 + c);
  float qx = bf2f(q4.x), qy = bf2f(q4.y), qz = bf2f(q4.z), qw = bf2f(q4.w);
  float px = bf2f(p4.x), py = bf2f(p4.y), pz = bf2f(p4.z), pw = bf2f(p4.w);
  // qbt inline: Σ_c q[c]*bt[c] over this head's 16 lanes
  float pb = qx * ldf(bt, c + 0, fbf);
  pb += qy * ldf(bt, c + 1, fbf);
  pb += qz * ldf(bt, c + 2, fbf);
  pb += qw * ldf(bt, c + 3, fbf);
  pb += __shfl_xor(pb, 1);
  pb += __shfl_xor(pb, 2);
  pb += __shfl_xor(pb, 4);
  pb += __shfl_xor(pb, 8);
  float qb = pb;
  int jb = c & 63;
  int kvoff = 256 + lane * 8;

  float m = -INFINITY, denom = 0.f;
  float acc0 = 0.f, acc1 = 0.f, acc2 = 0.f, acc3 = 0.f;

#define ALPHA_OF(kv, t4, out_a, okflag)                                        \
  {                                                                            \
    float s = qx * bf2f((kv)[0]) + __half2float(*(__half*)&(t4).x) * px;       \
    s += qy * bf2f((kv)[1]) + __half2float(*(__half*)&(t4).y) * py;            \
    s += qz * bf2f((kv)[2]) + __half2float(*(__half*)&(t4).z) * pz;            \
    s += qw * bf2f((kv)[3]) + __half2float(*(__half*)&(t4).w) * pw;            \
    s += __shfl_xor(s, 1);                                                     \
    s += __shfl_xor(s, 2);                                                     \
    s += __shfl_xor(s, 4);                                                     \
    s += __shfl_xor(s, 8);                                                     \
    out_a = (okflag) ? (s + qb) * 0.125f : 0.f;                                \
  }

#define STATE_UPDATE(a, kv, okflag)                                            \
  {                                                                            \
    float ea;                                                                  \
    if ((a) > m) {                                                             \
      float sc = __expf(m - (a));                                              \
      denom *= sc;                                                             \
      acc0 *= sc; acc1 *= sc; acc2 *= sc; acc3 *= sc;                          \
      m = (a);                                                                 \
      ea = 1.0f;                                                               \
    } else {                                                                   \
      ea = __expf((a) - m);                                                    \
    }                                                                          \
    denom += ea;                                                               \
    if (okflag) {                                                              \
      acc0 += ea * bf2f((kv)[4]);                                              \
      acc1 += ea * bf2f((kv)[5]);                                              \
      acc2 += ea * bf2f((kv)[6]);                                              \
      acc3 += ea * bf2f((kv)[7]);                                              \
    }                                                                          \
  }

  int p = s0;
  for (; p + 3 < s1; p += 4) {
    int srcA = ssrc[p], srcB = ssrc[p + 1], srcC = ssrc[p + 2], srcD = ssrc[p + 3];
    bool okA = (unsigned)srcA < NN, okB = (unsigned)srcB < NN;
    bool okC = (unsigned)srcC < NN, okD = (unsigned)srcD < NN;
    if (!okA) srcA = 0;
    if (!okB) srcB = 0;
    if (!okC) srcC = 0;
    if (!okD) srcD = 0;
    u16x8 kvA = *(const u16x8*)(qkvp + (size_t)srcA * NB + kvoff);
    u16x8 kvB = *(const u16x8*)(qkvp + (size_t)srcB * NB + kvoff);
    u16x8 kvC = *(const u16x8*)(qkvp + (size_t)srcC * NB + kvoff);
    u16x8 kvD = *(const u16x8*)(qkvp + (size_t)srcD * NB + kvoff);
    ushort4 tA = *(const ushort4*)(te_s + (size_t)p * 64 + jb);
    ushort4 tB = *(const ushort4*)(te_s + (size_t)(p + 1) * 64 + jb);
    ushort4 tC = *(const ushort4*)(te_s + (size_t)(p + 2) * 64 + jb);
    ushort4 tD = *(const ushort4*)(te_s + (size_t)(p + 3) * 64 + jb);

    float aA, aB, aC, aD;
    ALPHA_OF(kvA, tA, aA, okA)
    ALPHA_OF(kvB, tB, aB, okB)
    ALPHA_OF(kvC, tC, aC, okC)
    ALPHA_OF(kvD, tD, aD, okD)
    STATE_UPDATE(aA, kvA, okA)
    STATE_UPDATE(aB, kvB, okB)
    STATE_UPDATE(aC, kvC, okC)
    STATE_UPDATE(aD, kvD, okD)
  }
  for (; p < s1; ++p) {
    int src = ssrc[p];
    bool ok = (unsigned)src < NN;
    if (!ok) src = 0;
    u16x8 kv = *(const u16x8*)(qkvp + (size_t)src * NB + kvoff);
    ushort4 t4 = *(const ushort4*)(te_s + (size_t)p * 64 + jb);
    float a;
    ALPHA_OF(kv, t4, a, ok)
    STATE_UPDATE(a, kv, ok)
  }
#undef ALPHA_OF
#undef STATE_UPDATE

  float inv = 1.f / (denom + 1e-16f);
  ushort4 r;
  r.x = f2bf(fmaxf(acc0 * inv, 0.f));
  r.y = f2bf(fmaxf(acc1 * inv, 0.f));
  r.z = f2bf(fmaxf(acc2 * inv, 0.f));
  r.w = f2bf(fmaxf(acc3 * inv, 0.f));
  *(ushort4*)(xout + (size_t)n * HC + c) = r;
}

// ---------------- y[n] = x[n,:] . wc ----------------
__global__ __launch_bounds__(256) void xwc_kernel(
    const int* __restrict__ flags, const u16* __restrict__ x,
    const void* __restrict__ wc, float* __restrict__ y) {
  bool fbf = flags[1] != 0;
  int n = blockIdx.x * 4 + (threadIdx.x >> 6);
  if (n >= NN) return;
  int lane = threadIdx.x & 63;
  int c = lane * 4;
  ushort4 x4 = *(const ushort4*)(x + (size_t)n * HC + c);
  float s = bf2f(x4.x) * ldf(wc, c + 0, fbf);
  s += bf2f(x4.y) * ldf(wc, c + 1, fbf);
  s += bf2f(x4.z) * ldf(wc, c + 2, fbf);
  s += bf2f(x4.w) * ldf(wc, c + 3, fbf);
  for (int off = 32; off; off >>= 1) s += __shfl_xor(s, off);
  if (lane == 0) y[n] = s;
}

// ---------------- out[e] = y[src] + y[dst] + bc ----------------
__global__ __launch_bounds__(256) void final2_kernel(
    const int* __restrict__ flags, const void* __restrict__ eidx,
    const float* __restrict__ y, const void* __restrict__ bc,
    void* __restrict__ out) {
  bool is64 = flags[0] != 0, fbf = flags[1] != 0;
  int e = blockIdx.x * 256 + threadIdx.x;
  if (e >= NE) return;
  int src = ldsrc(eidx, e, is64);
  int dst = lddst(eidx, e, is64);
  if ((unsigned)src >= NN) src = 0;
  if ((unsigned)dst >= NN) dst = 0;
  stout(out, e, y[src] + y[dst] + ldf(bc, 0, fbf), fbf);
}

extern "C" void kernel_launch(void* const* d_in, const int* in_sizes, int n_in,
                              void* d_out, int out_size, void* d_ws, size_t ws_size,
                              hipStream_t stream) {
  const void* eidx  = d_in[0];
  const void* rawt  = d_in[1];
  const void* noise = d_in[2];
  const void* nemb  = d_in[3];
  const void *wq1 = d_in[4],  *bq1 = d_in[5];
  const void *wk1 = d_in[6],  *bk1 = d_in[7];
  const void *wv1 = d_in[8],  *bv1 = d_in[9];
  const void *wt1 = d_in[10], *bt1 = d_in[11];
  const void *wq2 = d_in[12], *bq2 = d_in[13];
  const void *wk2 = d_in[14], *bk2 = d_in[15];
  const void *wv2 = d_in[16], *bv2 = d_in[17];
  const void *wt2 = d_in[18], *bt2 = d_in[19];
  const void *wcp = d_in[20], *bcp = d_in[21];

  char* ws = (char*)d_ws;
  size_t off = 0;
  auto alloc = [&](size_t bytes) -> void* {
    void* p = ws + off;
    off += (bytes + 255) & ~(size_t)255;
    return p;
  };
  int*   flags  = (int*)alloc(256);
  float* divt   = (float*)alloc(256);
  u16*   WtBig  = (u16*)alloc((size_t)NB * HC * 2);
  float* biasBig= (float*)alloc((size_t)NB * 4);
  u16*   qkvp   = (u16*)alloc((size_t)NN * NB * 2);
  u16*   x1     = (u16*)alloc((size_t)NN * HC * 2);
  u16*   x2     = (u16*)alloc((size_t)NN * HC * 2);
  float* ynode  = (float*)alloc((size_t)NN * 4);
  int* offsets  = (int*)alloc((size_t)(NN + 1) * 4);
  int* cursor   = (int*)alloc((size_t)NN * 4);
  int* bsum     = (int*)alloc(256 * 4);
  int* ssrc     = (int*)alloc((size_t)NE * 4);
  float* stt    = (float*)alloc((size_t)NE * 4);
  u16* te_s     = (u16*)alloc((size_t)NE * 64 * 2);
  size_t need = off;

  int gN = (NN + 255) / 256, gE = (NE + 255) / 256;
  int nb = (NN + 255) / 256;

  if (ws_size < 1024) {
    raw_sentinel_kernel<<<gE, 256, 0, stream>>>((u16*)d_out);
    return;
  }
  devinit_kernel<<<1, 64, 0, stream>>>(eidx, nemb, flags, divt);
  if (need > ws_size) {
    sentinel_kernel<<<gE, 256, 0, stream>>>(flags, d_out);
    return;
  }

  // CSR by dst (+ sorted src / time)
  zero_kernel<<<gN, 256, 0, stream>>>(cursor, NN);
  hist_kernel<<<gE, 256, 0, stream>>>(flags, eidx, cursor);
  scan1_kernel<<<nb, 256, 0, stream>>>(cursor, offsets, bsum, NN);
  scan2_kernel<<<1, 256, 0, stream>>>(bsum, offsets, nb, NN);
  scan3_kernel<<<nb, 256, 0, stream>>>(offsets, bsum, cursor, NN);
  fill_kernel<<<gE, 256, 0, stream>>>(flags, eidx, rawt, noise, cursor, ssrc, stt);

  int gTe = (NE * 32 + 255) / 256;
  te_kernel<<<gTe, 256, 0, stream>>>(stt, divt, te_s);   // once for both layers

  dim3 ggemm((NN + 63) / 64, NB / 64);   // 313 x 16
  dim3 gt1(NIN / 64, 4, 3), gt2(HC / 64, 4, 3);
  int gNode = (NN + 3) / 4;

  // ---- Layer 1 (A = raw node_emb, K=128) ----
  transw3_kernel<<<gt1, 256, 0, stream>>>(flags, wq1, wk1, wv1, WtBig, NIN);
  wcombbias_kernel<<<260, 256, 0, stream>>>(flags, wt1, WtBig, WtBig + (size_t)768 * NIN,
                                            bq1, bk1, bv1, biasBig, NIN);
  gemm_mfma<false><<<ggemm, 256, 0, stream>>>(flags, nemb, WtBig, biasBig, qkvp, NN, NIN);
  aggfused_kernel<<<gNode, 256, 0, stream>>>(flags, ssrc, offsets, te_s, qkvp, bt1, x1);

  // ---- Layer 2 (A = bf16 x1, K=256) ----
  transw3_kernel<<<gt2, 256, 0, stream>>>(flags, wq2, wk2, wv2, WtBig, HC);
  wcombbias_kernel<<<260, 256, 0, stream>>>(flags, wt2, WtBig, WtBig + (size_t)768 * HC,
                                            bq2, bk2, bv2, biasBig, HC);
  gemm_mfma<true><<<ggemm, 256, 0, stream>>>(flags, x1, WtBig, biasBig, qkvp, NN, HC);
  aggfused_kernel<<<gNode, 256, 0, stream>>>(flags, ssrc, offsets, te_s, qkvp, bt2, x2);

  // Edge scorer: y[n] = x2[n].wc, then out[e] = y[src]+y[dst]+bc
  xwc_kernel<<<gNode, 256, 0, stream>>>(flags, x2, wcp, ynode);
  final2_kernel<<<gE, 256, 0, stream>>>(flags, eidx, ynode, bcp, d_out);
}